// Round 6
// baseline (901.828 us; speedup 1.0000x reference)
//
#include <hip/hip_runtime.h>

// VectorQuantizer: x[16384][64] fp32, codebook[8192][64] fp32
// out = concat(discrete one-hot [16384][8192] fp32, quantized [16384][64] fp32)
// argmin_k ||x-c_k||^2 == argmax_k (x.c_k - 0.5||c_k||^2)
//
// r18 -> r19: INSTRUMENTATION ROUND. Five structural rounds moved nothing;
// the bottleneck phase has never appeared in the rocprof top-5 (the ~347us
// harness poison fills occupy every slot). This round makes the two suspect
// phases LONGER than the fills so they surface with their own counters:
//   k_main: the compute/argmax loop runs 3 IDENTICAL passes (asm reg+memory
//           barriers between passes prevent CSE/DCE; argmax over repeated
//           identical passes is bit-identical since '>' keeps the first).
//           Its row reveals M, FETCH (read source), MfmaUtil/VALUBusy/Occ.
//   k_zero: plain-store zero fill runs 6 passes (memory clobber between
//           passes prevents dead-store elim). Its row reveals Z and, via
//           FETCH_SIZE, whether stores write-allocate (RMW doubling HBM
//           traffic -- the leading theory for why every fill variant ran
//           at ~2.9 TB/s instead of the harness's 6.2).
// Output remains exactly correct (absmax 0). Next round applies the fix
// the counters dictate, dropping the extra passes.

#define NROWS 16384
#define KCODES 8192
#define DDIM 64
#define RPB 32                    // rows per block
#define CWAVES 4                  // waves per block (256 threads)
#define WCODES (KCODES / CWAVES)  // 2048 codes per wave
#define WTILES (WCODES / 16)      // 128 tiles per wave
#define MPASS 3                   // compute passes (instrumentation)
#define ZPASS 6                   // zero-fill passes (instrumentation)

typedef float    f32x4 __attribute__((ext_vector_type(4)));
typedef _Float16 f16x8 __attribute__((ext_vector_type(8)));

// ---------------- kernel 0: fused pack + cn2 ----------------
__global__ __launch_bounds__(256) void k_prep(const float* __restrict__ cb,
                                              f16x8* __restrict__ packed,
                                              float* __restrict__ cn2) {
    int tid = blockIdx.x * 256 + threadIdx.x;   // 0..32767
    int Tg = tid >> 6, L = tid & 63;
    int lane15 = L & 15, quad = L >> 4;
    int code = Tg * 16 + lane15;
    const float* p = cb + (size_t)code * DDIM + quad * 8;
    f16x8 h0, l0, h1, l1;
    float s = 0.f;
#pragma unroll
    for (int j = 0; j < 8; ++j) {
        float v = p[j];
        _Float16 h = (_Float16)v;
        h0[j] = h; l0[j] = (_Float16)(v - (float)h);
        s = fmaf(v, v, s);
        float w = p[32 + j];
        _Float16 h2 = (_Float16)w;
        h1[j] = h2; l1[j] = (_Float16)(w - (float)h2);
        s = fmaf(w, w, s);
    }
    s += __shfl_xor(s, 16, 64);
    s += __shfl_xor(s, 32, 64);
    if (quad == 0) cn2[code] = 0.5f * s;
    f16x8* out = packed + (size_t)Tg * 256 + L;
    out[0]   = h0;
    out[64]  = h1;
    out[128] = l0;
    out[192] = l1;
}

// ---------------- kernel 1: compute-only MFMA + argmax (x MPASS) ----------------
__global__ __launch_bounds__(256, 2) void k_main(const float* __restrict__ x,
                                                 const float* __restrict__ cb,
                                                 const f16x8* __restrict__ packed,
                                                 const float* __restrict__ cn2,
                                                 int* __restrict__ sidx_ws,
                                                 float* __restrict__ quantized) {
    const int t = threadIdx.x;
    const int L = t & 63;
    const int w = t >> 6;                 // wave = code quarter (ascending codes)
    const int row0 = blockIdx.x * RPB;
    const int lane15 = L & 15;
    const int quad = L >> 4;

    // ---- A fragments: two row groups, exact hi/lo split ----
    const float* xa = x + (size_t)(row0 + lane15) * DDIM + quad * 8;
    const float* xb = xa + 16 * DDIM;
    f16x8 Ah0, Al0, Ah1, Al1, Bh0, Bl0, Bh1, Bl1;
#pragma unroll
    for (int j = 0; j < 8; ++j) {
        float v = xa[j];        _Float16 h = (_Float16)v;
        Ah0[j] = h; Al0[j] = (_Float16)(v - (float)h);
        v = xa[32 + j];         h = (_Float16)v;
        Ah1[j] = h; Al1[j] = (_Float16)(v - (float)h);
        v = xb[j];              h = (_Float16)v;
        Bh0[j] = h; Bl0[j] = (_Float16)(v - (float)h);
        v = xb[32 + j];         h = (_Float16)v;
        Bh1[j] = h; Bl1[j] = (_Float16)(v - (float)h);
    }

    float bvA[4], bvB[4];
    int   biA[4], biB[4];
#pragma unroll
    for (int r = 0; r < 4; ++r) { bvA[r] = bvB[r] = -3.4e38f; biA[r] = biB[r] = 0; }

    const int code0 = w * WCODES;
    const f16x8* pbase = packed + (size_t)(code0 >> 4) * 256 + L;

    for (int pass = 0; pass < MPASS; ++pass) {
        // Block cross-pass CSE/DCE: A-frags become "unknown new values"
        // (no-op at runtime), and memory is clobbered so all packed/cn2
        // loads re-execute. Results are bit-identical each pass; argmax
        // '>' keeps the first occurrence -> final bv/bi identical to 1 pass.
        asm volatile("" : "+v"(Ah0), "+v"(Al0), "+v"(Ah1), "+v"(Al1),
                          "+v"(Bh0), "+v"(Bl0), "+v"(Bh1), "+v"(Bl1));
        asm volatile("" ::: "memory");

        // preload tiles 0 (cur) and 1 (nxt): B frags + cn
        f16x8 ch0 = pbase[0], ch1 = pbase[64], cl0 = pbase[128], cl1 = pbase[192];
        float cn = cn2[code0 + lane15];
        const f16x8* p1 = pbase + 256;
        f16x8 nh0 = p1[0], nh1 = p1[64], nl0 = p1[128], nl1 = p1[192];
        float cnn = cn2[code0 + 16 + lane15];

        for (int i = 0; i < WTILES; ++i) {
            // prefetch tile i+2 (depth-2 reach covers L2 latency)
            const int i2 = (i + 2 < WTILES) ? i + 2 : WTILES - 1;
            const f16x8* pm = pbase + (size_t)i2 * 256;
            f16x8 mh0 = pm[0], mh1 = pm[64], ml0 = pm[128], ml1 = pm[192];
            float cnm = cn2[code0 + i2 * 16 + lane15];

            // compute current tile (order bit-identical to r13)
            f32x4 accA = {-cn, -cn, -cn, -cn};
            f32x4 accB = accA;
            accA = __builtin_amdgcn_mfma_f32_16x16x32_f16(Ah0, ch0, accA, 0, 0, 0);
            accB = __builtin_amdgcn_mfma_f32_16x16x32_f16(Bh0, ch0, accB, 0, 0, 0);
            accA = __builtin_amdgcn_mfma_f32_16x16x32_f16(Ah1, ch1, accA, 0, 0, 0);
            accB = __builtin_amdgcn_mfma_f32_16x16x32_f16(Bh1, ch1, accB, 0, 0, 0);
            accA = __builtin_amdgcn_mfma_f32_16x16x32_f16(Al0, ch0, accA, 0, 0, 0);
            accB = __builtin_amdgcn_mfma_f32_16x16x32_f16(Bl0, ch0, accB, 0, 0, 0);
            accA = __builtin_amdgcn_mfma_f32_16x16x32_f16(Al1, ch1, accA, 0, 0, 0);
            accB = __builtin_amdgcn_mfma_f32_16x16x32_f16(Bl1, ch1, accB, 0, 0, 0);
            accA = __builtin_amdgcn_mfma_f32_16x16x32_f16(Ah0, cl0, accA, 0, 0, 0);
            accB = __builtin_amdgcn_mfma_f32_16x16x32_f16(Bh0, cl0, accB, 0, 0, 0);
            accA = __builtin_amdgcn_mfma_f32_16x16x32_f16(Ah1, cl1, accA, 0, 0, 0);
            accB = __builtin_amdgcn_mfma_f32_16x16x32_f16(Bh1, cl1, accB, 0, 0, 0);
            accA = __builtin_amdgcn_mfma_f32_16x16x32_f16(Al0, cl0, accA, 0, 0, 0);
            accB = __builtin_amdgcn_mfma_f32_16x16x32_f16(Bl0, cl0, accB, 0, 0, 0);
            accA = __builtin_amdgcn_mfma_f32_16x16x32_f16(Al1, cl1, accA, 0, 0, 0);
            accB = __builtin_amdgcn_mfma_f32_16x16x32_f16(Bl1, cl1, accB, 0, 0, 0);

            const int vcode = code0 + i * 16 + lane15;
#pragma unroll
            for (int r = 0; r < 4; ++r) {
                if (accA[r] > bvA[r]) { bvA[r] = accA[r]; biA[r] = vcode; }
                if (accB[r] > bvB[r]) { bvB[r] = accB[r]; biB[r] = vcode; }
            }

            // rotate pipeline stages
            ch0 = nh0; ch1 = nh1; cl0 = nl0; cl1 = nl1; cn = cnn;
            nh0 = mh0; nh1 = mh1; nl0 = ml0; nl1 = ml1; cnn = cnm;
        }
    }

    // ---- 16-lane butterfly per quad, then cross-wave LDS reduce ----
    __shared__ float rv[RPB][CWAVES + 1];
    __shared__ int   ri[RPB][CWAVES + 1];
    __shared__ int   sidx[RPB];
#pragma unroll
    for (int r = 0; r < 4; ++r) {
        float vA = bvA[r], vB = bvB[r];
        int  iA = biA[r], iB = biB[r];
#pragma unroll
        for (int m = 1; m < 16; m <<= 1) {
            float oA = __shfl_xor(vA, m, 64); int xA = __shfl_xor(iA, m, 64);
            if (oA > vA || (oA == vA && xA < iA)) { vA = oA; iA = xA; }
            float oB = __shfl_xor(vB, m, 64); int xB = __shfl_xor(iB, m, 64);
            if (oB > vB || (oB == vB && xB < iB)) { vB = oB; iB = xB; }
        }
        if (lane15 == 0) {
            rv[quad * 4 + r][w] = vA;      ri[quad * 4 + r][w] = iA;
            rv[16 + quad * 4 + r][w] = vB; ri[16 + quad * 4 + r][w] = iB;
        }
    }
    __syncthreads();
    if (t < RPB) {
        float bv = rv[t][0];
        int   bi = ri[t][0];
#pragma unroll
        for (int w2 = 1; w2 < CWAVES; ++w2) {  // ascending wave = ascending codes
            float v = rv[t][w2];
            int  id = ri[t][w2];
            if (v > bv || (v == bv && id < bi)) { bv = v; bi = id; }
        }
        sidx[t] = bi;
        sidx_ws[row0 + t] = bi;
    }
    __syncthreads();

    // ---- quantized gather: 32 rows x 16 float4, coalesced ----
#pragma unroll
    for (int e = t; e < RPB * 16; e += 256) {
        int r = e >> 4, c = e & 15;
        float4 v = *((const float4*)(cb + (size_t)sidx[r] * DDIM) + c);
        *((float4*)(quantized + (size_t)(row0 + r) * DDIM) + c) = v;
    }
}

// ---------------- kernel 2: plain-store zero fill (x ZPASS) ----------------
// 4096 blocks x 256 threads, contiguous 128 KB per block per pass.
// Memory clobber between passes prevents dead-store elimination, so the
// dispatch duration = ZPASS x true fill time and FETCH_SIZE reveals RMW.
__global__ __launch_bounds__(256) void k_zero(f32x4* __restrict__ dst) {
    const f32x4 zero4 = {0.f, 0.f, 0.f, 0.f};
    f32x4* p = dst + (size_t)blockIdx.x * (32 * 256) + threadIdx.x;
    for (int pass = 0; pass < ZPASS; ++pass) {
        asm volatile("" ::: "memory");
#pragma unroll
        for (int j = 0; j < 32; ++j)
            p[j * 256] = zero4;
    }
}

// ---------------- kernel 3: scatter the 1.0s ----------------
__global__ __launch_bounds__(256) void k_scatter(const int* __restrict__ sidx_ws,
                                                 float* __restrict__ discrete) {
    int row = blockIdx.x * 256 + threadIdx.x;   // 64 blocks x 256 = 16384
    discrete[(size_t)row * KCODES + sidx_ws[row]] = 1.0f;
}

extern "C" void kernel_launch(void* const* d_in, const int* in_sizes, int n_in,
                              void* d_out, int out_size, void* d_ws, size_t ws_size,
                              hipStream_t stream) {
    const float* x  = (const float*)d_in[0];   // 16*32*32*64
    const float* cb = (const float*)d_in[1];   // 8192*64

    float* discrete  = (float*)d_out;                          // 16384*8192
    float* quantized = (float*)d_out + (size_t)NROWS * KCODES; // 16384*64

    // workspace layout: cn2 (32 KB) | packed B-frags (2 MB) | sidx (64 KB).
    float* cn2    = (float*)d_ws;              // 8192 floats
    f16x8* packed = (f16x8*)(cn2 + KCODES);    // 2 MB
    int*   sidx   = (int*)((char*)packed + (size_t)(KCODES / 16) * 256 * sizeof(f16x8));

    k_prep<<<(KCODES / 16) * 64 / 256, 256, 0, stream>>>(cb, packed, cn2);
    k_main<<<NROWS / RPB, CWAVES * 64, 0, stream>>>(x, cb, packed, cn2,
                                                    sidx, quantized);
    k_zero<<<(NROWS * KCODES / 4) / (32 * 256), 256, 0, stream>>>((f32x4*)discrete);
    k_scatter<<<NROWS / 256, 256, 0, stream>>>(sidx, discrete);
}

// Round 7
// 588.000 us; speedup vs baseline: 1.5337x; 1.5337x over previous
//
#include <hip/hip_runtime.h>
#include <hip/hip_cooperative_groups.h>

// VectorQuantizer: x[16384][64] fp32, codebook[8192][64] fp32
// out = concat(discrete one-hot [16384][8192] fp32, quantized [16384][64] fp32)
// argmin_k ||x-c_k||^2 == argmax_k (x.c_k - 0.5||c_k||^2)
//
// r19 -> r20: r19's instrumentation bounded the true kernel costs (compute
// M < 115us, 536MB fill Z < 57us -- neither surfaced above the 344us fills
// even at 3x/6x). Refit of all rounds: window = 347us harness poison fill
// + ~30us PER DISPATCH BOUNDARY + kernels; the fused kernel is already at
// its ~87-110us store-drain bound. Remaining lever = dispatch count.
// r20 = ONE cooperative kernel: phase A packs cb (blocks 0..127, exact
// k_prep body), grid.sync(), phase B = r13's proven fused MFMA/argmax/
// NT-zero/one-hot/quantized loop verbatim. __launch_bounds__(256,2)
// guarantees 2 blocks/CU co-residency for the coop launch (512 blocks).
// Fallback to the two-dispatch r13 path if coop launch is rejected.
// Exact fp32 dots via fp16 hi/lo split, 16 MFMA terms, bit-identical order.

#define NROWS 16384
#define KCODES 8192
#define DDIM 64
#define RPB 32                    // rows per block
#define CWAVES 4                  // waves per block (256 threads)
#define WCODES (KCODES / CWAVES)  // 2048 codes per wave
#define WTILES (WCODES / 16)      // 128 tiles per wave
#define PREP_BLOCKS ((KCODES / 16) * 64 / 256)   // 128

typedef float    f32x4 __attribute__((ext_vector_type(4)));
typedef _Float16 f16x8 __attribute__((ext_vector_type(8)));

// ---------------- phase A: fused pack + cn2 (exact k_prep body) ----------------
// thread (Tg, L): code = Tg*16 + (L&15), k-slice = (L>>4)*8 (+32).
// packed[Tg][frag][lane]: frag 0=hi k0..31, 1=hi k32..63, 2=lo k0..31, 3=lo k32..63.
__device__ __forceinline__ void prep_body(int tid, const float* __restrict__ cb,
                                          f16x8* __restrict__ packed,
                                          float* __restrict__ cn2) {
    int Tg = tid >> 6, L = tid & 63;
    int lane15 = L & 15, quad = L >> 4;
    int code = Tg * 16 + lane15;
    const float* p = cb + (size_t)code * DDIM + quad * 8;
    f16x8 h0, l0, h1, l1;
    float s = 0.f;
#pragma unroll
    for (int j = 0; j < 8; ++j) {
        float v = p[j];
        _Float16 h = (_Float16)v;
        h0[j] = h; l0[j] = (_Float16)(v - (float)h);
        s = fmaf(v, v, s);
        float w = p[32 + j];
        _Float16 h2 = (_Float16)w;
        h1[j] = h2; l1[j] = (_Float16)(w - (float)h2);
        s = fmaf(w, w, s);
    }
    s += __shfl_xor(s, 16, 64);
    s += __shfl_xor(s, 32, 64);
    if (quad == 0) cn2[code] = 0.5f * s;
    f16x8* out = packed + (size_t)Tg * 256 + L;
    out[0]   = h0;
    out[64]  = h1;
    out[128] = l0;
    out[192] = l1;
}

// ---------------- phase B: r13 fused MFMA + argmax + NT zero + one-hot + quantized ----------------
__device__ __forceinline__ void main_body(const float* __restrict__ x,
                                          const float* __restrict__ cb,
                                          const f16x8* __restrict__ packed,
                                          const float* __restrict__ cn2,
                                          float* __restrict__ discrete,
                                          float* __restrict__ quantized) {
    const int t = threadIdx.x;
    const int L = t & 63;
    const int w = t >> 6;                 // wave = code quarter (ascending codes)
    const int row0 = blockIdx.x * RPB;
    const int lane15 = L & 15;
    const int quad = L >> 4;

    // ---- A fragments: two row groups, exact hi/lo split ----
    const float* xa = x + (size_t)(row0 + lane15) * DDIM + quad * 8;
    const float* xb = xa + 16 * DDIM;
    f16x8 Ah0, Al0, Ah1, Al1, Bh0, Bl0, Bh1, Bl1;
#pragma unroll
    for (int j = 0; j < 8; ++j) {
        float v = xa[j];        _Float16 h = (_Float16)v;
        Ah0[j] = h; Al0[j] = (_Float16)(v - (float)h);
        v = xa[32 + j];         h = (_Float16)v;
        Ah1[j] = h; Al1[j] = (_Float16)(v - (float)h);
        v = xb[j];              h = (_Float16)v;
        Bh0[j] = h; Bl0[j] = (_Float16)(v - (float)h);
        v = xb[32 + j];         h = (_Float16)v;
        Bh1[j] = h; Bl1[j] = (_Float16)(v - (float)h);
    }

    float bvA[4], bvB[4];
    int   biA[4], biB[4];
#pragma unroll
    for (int r = 0; r < 4; ++r) { bvA[r] = bvB[r] = -3.4e38f; biA[r] = biB[r] = 0; }

    const f32x4 zero4 = {0.f, 0.f, 0.f, 0.f};
    const int code0 = w * WCODES;
    const f16x8* pbase = packed + (size_t)(code0 >> 4) * 256 + L;

    // preload tiles 0 (cur) and 1 (nxt): B frags + cn
    f16x8 ch0 = pbase[0], ch1 = pbase[64], cl0 = pbase[128], cl1 = pbase[192];
    float cn = cn2[code0 + lane15];
    const f16x8* p1 = pbase + 256;
    f16x8 nh0 = p1[0], nh1 = p1[64], nl0 = p1[128], nl1 = p1[192];
    float cnn = cn2[code0 + 16 + lane15];

    f32x4* zdst = (f32x4*)(discrete + (size_t)row0 * KCODES);   // 65536 f32x4/block

    for (int i = 0; i < WTILES; ++i) {
        // ---- prefetch tile i+2 (loads precede stores; covers L2 latency) ----
        const int i2 = (i + 2 < WTILES) ? i + 2 : WTILES - 1;
        const f16x8* pm = pbase + (size_t)i2 * 256;
        f16x8 mh0 = pm[0], mh1 = pm[64], ml0 = pm[128], ml1 = pm[192];
        float cnm = cn2[code0 + i2 * 16 + lane15];

        // ---- NT zero-fill: 2 f32x4 per thread per tile (65536 total/block) ----
        {
            int g = i * 512 + t;
            __builtin_nontemporal_store(zero4, zdst + g);
            __builtin_nontemporal_store(zero4, zdst + g + 256);
        }

        // ---- compute current tile (order bit-identical to r13) ----
        const int ct = code0 + i * 16;
        f32x4 accA = {-cn, -cn, -cn, -cn};
        f32x4 accB = accA;
        accA = __builtin_amdgcn_mfma_f32_16x16x32_f16(Ah0, ch0, accA, 0, 0, 0);
        accB = __builtin_amdgcn_mfma_f32_16x16x32_f16(Bh0, ch0, accB, 0, 0, 0);
        accA = __builtin_amdgcn_mfma_f32_16x16x32_f16(Ah1, ch1, accA, 0, 0, 0);
        accB = __builtin_amdgcn_mfma_f32_16x16x32_f16(Bh1, ch1, accB, 0, 0, 0);
        accA = __builtin_amdgcn_mfma_f32_16x16x32_f16(Al0, ch0, accA, 0, 0, 0);
        accB = __builtin_amdgcn_mfma_f32_16x16x32_f16(Bl0, ch0, accB, 0, 0, 0);
        accA = __builtin_amdgcn_mfma_f32_16x16x32_f16(Al1, ch1, accA, 0, 0, 0);
        accB = __builtin_amdgcn_mfma_f32_16x16x32_f16(Bl1, ch1, accB, 0, 0, 0);
        accA = __builtin_amdgcn_mfma_f32_16x16x32_f16(Ah0, cl0, accA, 0, 0, 0);
        accB = __builtin_amdgcn_mfma_f32_16x16x32_f16(Bh0, cl0, accB, 0, 0, 0);
        accA = __builtin_amdgcn_mfma_f32_16x16x32_f16(Ah1, cl1, accA, 0, 0, 0);
        accB = __builtin_amdgcn_mfma_f32_16x16x32_f16(Bh1, cl1, accB, 0, 0, 0);
        accA = __builtin_amdgcn_mfma_f32_16x16x32_f16(Al0, cl0, accA, 0, 0, 0);
        accB = __builtin_amdgcn_mfma_f32_16x16x32_f16(Bl0, cl0, accB, 0, 0, 0);
        accA = __builtin_amdgcn_mfma_f32_16x16x32_f16(Al1, cl1, accA, 0, 0, 0);
        accB = __builtin_amdgcn_mfma_f32_16x16x32_f16(Bl1, cl1, accB, 0, 0, 0);

        const int vcode = ct + lane15;
#pragma unroll
        for (int r = 0; r < 4; ++r) {
            if (accA[r] > bvA[r]) { bvA[r] = accA[r]; biA[r] = vcode; }
            if (accB[r] > bvB[r]) { bvB[r] = accB[r]; biB[r] = vcode; }
        }

        // ---- rotate pipeline stages ----
        ch0 = nh0; ch1 = nh1; cl0 = nl0; cl1 = nl1; cn = cnn;
        nh0 = mh0; nh1 = mh1; nl0 = ml0; nl1 = ml1; cnn = cnm;
    }

    // ---- 16-lane butterfly per quad, then cross-wave LDS reduce ----
    __shared__ float rv[RPB][CWAVES + 1];
    __shared__ int   ri[RPB][CWAVES + 1];
    __shared__ int   sidx[RPB];
#pragma unroll
    for (int r = 0; r < 4; ++r) {
        float vA = bvA[r], vB = bvB[r];
        int  iA = biA[r], iB = biB[r];
#pragma unroll
        for (int m = 1; m < 16; m <<= 1) {
            float oA = __shfl_xor(vA, m, 64); int xA = __shfl_xor(iA, m, 64);
            if (oA > vA || (oA == vA && xA < iA)) { vA = oA; iA = xA; }
            float oB = __shfl_xor(vB, m, 64); int xB = __shfl_xor(iB, m, 64);
            if (oB > vB || (oB == vB && xB < iB)) { vB = oB; iB = xB; }
        }
        if (lane15 == 0) {
            rv[quad * 4 + r][w] = vA;      ri[quad * 4 + r][w] = iA;
            rv[16 + quad * 4 + r][w] = vB; ri[16 + quad * 4 + r][w] = iB;
        }
    }
    __syncthreads();   // drains NT zero stores before the 1.0 write
    if (t < RPB) {
        float bv = rv[t][0];
        int   bi = ri[t][0];
#pragma unroll
        for (int w2 = 1; w2 < CWAVES; ++w2) {  // ascending wave = ascending codes
            float v = rv[t][w2];
            int  id = ri[t][w2];
            if (v > bv || (v == bv && id < bi)) { bv = v; bi = id; }
        }
        int row = row0 + t;
        sidx[t] = bi;
        discrete[(size_t)row * KCODES + bi] = 1.0f;
    }
    __syncthreads();

    // ---- fused quantized gather: 32 rows x 16 float4, coalesced ----
#pragma unroll
    for (int e = t; e < RPB * 16; e += 256) {
        int r = e >> 4, c = e & 15;
        float4 v = *((const float4*)(cb + (size_t)sidx[r] * DDIM) + c);
        *((float4*)(quantized + (size_t)(row0 + r) * DDIM) + c) = v;
    }
}

// ---------------- single cooperative kernel: prep -> grid.sync -> main ----------------
__global__ __launch_bounds__(256, 2) void k_all(const float* __restrict__ x,
                                                const float* __restrict__ cb,
                                                f16x8* __restrict__ packed,
                                                float* __restrict__ cn2,
                                                float* __restrict__ discrete,
                                                float* __restrict__ quantized) {
    if (blockIdx.x < PREP_BLOCKS)
        prep_body(blockIdx.x * 256 + threadIdx.x, cb, packed, cn2);
    cooperative_groups::this_grid().sync();
    main_body(x, cb, packed, cn2, discrete, quantized);
}

// ---------------- fallback two-dispatch path (r13 structure) ----------------
__global__ __launch_bounds__(256) void k_prep(const float* __restrict__ cb,
                                              f16x8* __restrict__ packed,
                                              float* __restrict__ cn2) {
    prep_body(blockIdx.x * 256 + threadIdx.x, cb, packed, cn2);
}

__global__ __launch_bounds__(256, 2) void k_main(const float* __restrict__ x,
                                                 const float* __restrict__ cb,
                                                 const f16x8* __restrict__ packed,
                                                 const float* __restrict__ cn2,
                                                 float* __restrict__ discrete,
                                                 float* __restrict__ quantized) {
    main_body(x, cb, packed, cn2, discrete, quantized);
}

extern "C" void kernel_launch(void* const* d_in, const int* in_sizes, int n_in,
                              void* d_out, int out_size, void* d_ws, size_t ws_size,
                              hipStream_t stream) {
    const float* x  = (const float*)d_in[0];   // 16*32*32*64
    const float* cb = (const float*)d_in[1];   // 8192*64

    float* discrete  = (float*)d_out;                          // 16384*8192
    float* quantized = (float*)d_out + (size_t)NROWS * KCODES; // 16384*64

    // workspace layout: cn2 (32 KB) | packed B-frags (2 MB).
    float* cn2    = (float*)d_ws;              // 8192 floats
    f16x8* packed = (f16x8*)(cn2 + KCODES);    // 2 MB

    void* args[] = { (void*)&x, (void*)&cb, (void*)&packed, (void*)&cn2,
                     (void*)&discrete, (void*)&quantized };
    hipError_t e = hipLaunchCooperativeKernel((void*)k_all,
                                              dim3(NROWS / RPB), dim3(CWAVES * 64),
                                              args, 0, stream);
    if (e != hipSuccess) {
        // coop launch unavailable (e.g. capture restriction): r13 path.
        k_prep<<<PREP_BLOCKS, 256, 0, stream>>>(cb, packed, cn2);
        k_main<<<NROWS / RPB, CWAVES * 64, 0, stream>>>(x, cb, packed, cn2,
                                                        discrete, quantized);
    }
}

// Round 8
// 542.540 us; speedup vs baseline: 1.6622x; 1.0838x over previous
//
#include <hip/hip_runtime.h>

// VectorQuantizer: x[16384][64] fp32, codebook[8192][64] fp32
// out = concat(discrete one-hot [16384][8192] fp32, quantized [16384][64] fp32)
// argmin_k ||x-c_k||^2 == argmax_k (x.c_k - 0.5||c_k||^2)
//
// r20 -> r21: model refit across all 8 rounds pins the compute loop at
// M ~= 113us (r17 decomposition; r19 bound 3M < 344) vs a ~45-50us
// max(MFMA-issue, L2-read) floor: it is MFMA-LATENCY-bound at 2 waves/SIMD
// (2 blocks/CU x 4 waves, Occupancy ~10%). r14's occupancy test was
// confounded (RPB 16 doubled L2 traffic). The clean lever: split the CODE
// axis across 8 waves instead of 4 -- 512-thread blocks, same 512 blocks,
// same per-block packed reads (no traffic change), 16 waves/CU = 4/SIMD =
// 8 independent MFMA chains per SIMD. Everything else is r13 verbatim:
// same per-tile 16-MFMA order, same interleaved NT zero stores (2/thread/
// tile), same argmax/tie rules, cross-wave reduce now over 8 waves in
// ascending code order -> bit-identical result, absmax 0.
// Exact fp32 dots via fp16 hi/lo split, 16 MFMA terms, bit-identical order.

#define NROWS 16384
#define KCODES 8192
#define DDIM 64
#define RPB 32                    // rows per block
#define CWAVES 8                  // waves per block (512 threads)
#define WCODES (KCODES / CWAVES)  // 1024 codes per wave
#define WTILES (WCODES / 16)      // 64 tiles per wave

typedef float    f32x4 __attribute__((ext_vector_type(4)));
typedef _Float16 f16x8 __attribute__((ext_vector_type(8)));

// ---------------- kernel 0: fused pack + cn2 ----------------
// thread (Tg, L): code = Tg*16 + (L&15), k-slice = (L>>4)*8 (+32).
// packed[Tg][frag][lane]: frag 0=hi k0..31, 1=hi k32..63, 2=lo k0..31, 3=lo k32..63.
__global__ __launch_bounds__(256) void k_prep(const float* __restrict__ cb,
                                              f16x8* __restrict__ packed,
                                              float* __restrict__ cn2) {
    int tid = blockIdx.x * 256 + threadIdx.x;   // 0..32767
    int Tg = tid >> 6, L = tid & 63;
    int lane15 = L & 15, quad = L >> 4;
    int code = Tg * 16 + lane15;
    const float* p = cb + (size_t)code * DDIM + quad * 8;
    f16x8 h0, l0, h1, l1;
    float s = 0.f;
#pragma unroll
    for (int j = 0; j < 8; ++j) {
        float v = p[j];
        _Float16 h = (_Float16)v;
        h0[j] = h; l0[j] = (_Float16)(v - (float)h);
        s = fmaf(v, v, s);
        float w = p[32 + j];
        _Float16 h2 = (_Float16)w;
        h1[j] = h2; l1[j] = (_Float16)(w - (float)h2);
        s = fmaf(w, w, s);
    }
    s += __shfl_xor(s, 16, 64);
    s += __shfl_xor(s, 32, 64);
    if (quad == 0) cn2[code] = 0.5f * s;
    f16x8* out = packed + (size_t)Tg * 256 + L;
    out[0]   = h0;
    out[64]  = h1;
    out[128] = l0;
    out[192] = l1;
}

// ---------------- kernel 1: MFMA + argmax + NT zero-fill + one-hot + quantized ----------------
__global__ __launch_bounds__(512, 2) void k_main(const float* __restrict__ x,
                                                 const float* __restrict__ cb,
                                                 const f16x8* __restrict__ packed,
                                                 const float* __restrict__ cn2,
                                                 float* __restrict__ discrete,
                                                 float* __restrict__ quantized) {
    const int t = threadIdx.x;            // 0..511
    const int L = t & 63;
    const int w = t >> 6;                 // wave 0..7 = code eighth (ascending)
    const int row0 = blockIdx.x * RPB;
    const int lane15 = L & 15;
    const int quad = L >> 4;

    // ---- A fragments: two row groups, exact hi/lo split (same rows all waves) ----
    const float* xa = x + (size_t)(row0 + lane15) * DDIM + quad * 8;
    const float* xb = xa + 16 * DDIM;
    f16x8 Ah0, Al0, Ah1, Al1, Bh0, Bl0, Bh1, Bl1;
#pragma unroll
    for (int j = 0; j < 8; ++j) {
        float v = xa[j];        _Float16 h = (_Float16)v;
        Ah0[j] = h; Al0[j] = (_Float16)(v - (float)h);
        v = xa[32 + j];         h = (_Float16)v;
        Ah1[j] = h; Al1[j] = (_Float16)(v - (float)h);
        v = xb[j];              h = (_Float16)v;
        Bh0[j] = h; Bl0[j] = (_Float16)(v - (float)h);
        v = xb[32 + j];         h = (_Float16)v;
        Bh1[j] = h; Bl1[j] = (_Float16)(v - (float)h);
    }

    float bvA[4], bvB[4];
    int   biA[4], biB[4];
#pragma unroll
    for (int r = 0; r < 4; ++r) { bvA[r] = bvB[r] = -3.4e38f; biA[r] = biB[r] = 0; }

    const f32x4 zero4 = {0.f, 0.f, 0.f, 0.f};
    const int code0 = w * WCODES;
    const f16x8* pbase = packed + (size_t)(code0 >> 4) * 256 + L;

    // preload tiles 0 (cur) and 1 (nxt): B frags + cn
    f16x8 ch0 = pbase[0], ch1 = pbase[64], cl0 = pbase[128], cl1 = pbase[192];
    float cn = cn2[code0 + lane15];
    const f16x8* p1 = pbase + 256;
    f16x8 nh0 = p1[0], nh1 = p1[64], nl0 = p1[128], nl1 = p1[192];
    float cnn = cn2[code0 + 16 + lane15];

    f32x4* zdst = (f32x4*)(discrete + (size_t)row0 * KCODES);   // 65536 f32x4/block

    for (int i = 0; i < WTILES; ++i) {
        // ---- prefetch tile i+2 (loads precede stores; covers L2 latency) ----
        const int i2 = (i + 2 < WTILES) ? i + 2 : WTILES - 1;
        const f16x8* pm = pbase + (size_t)i2 * 256;
        f16x8 mh0 = pm[0], mh1 = pm[64], ml0 = pm[128], ml1 = pm[192];
        float cnm = cn2[code0 + i2 * 16 + lane15];

        // ---- NT zero-fill: 2 f32x4 per thread per tile (64*512*2 = 65536/block) ----
        {
            int g = i * 1024 + t;
            __builtin_nontemporal_store(zero4, zdst + g);
            __builtin_nontemporal_store(zero4, zdst + g + 512);
        }

        // ---- compute current tile (order bit-identical to r13) ----
        const int ct = code0 + i * 16;
        f32x4 accA = {-cn, -cn, -cn, -cn};
        f32x4 accB = accA;
        accA = __builtin_amdgcn_mfma_f32_16x16x32_f16(Ah0, ch0, accA, 0, 0, 0);
        accB = __builtin_amdgcn_mfma_f32_16x16x32_f16(Bh0, ch0, accB, 0, 0, 0);
        accA = __builtin_amdgcn_mfma_f32_16x16x32_f16(Ah1, ch1, accA, 0, 0, 0);
        accB = __builtin_amdgcn_mfma_f32_16x16x32_f16(Bh1, ch1, accB, 0, 0, 0);
        accA = __builtin_amdgcn_mfma_f32_16x16x32_f16(Al0, ch0, accA, 0, 0, 0);
        accB = __builtin_amdgcn_mfma_f32_16x16x32_f16(Bl0, ch0, accB, 0, 0, 0);
        accA = __builtin_amdgcn_mfma_f32_16x16x32_f16(Al1, ch1, accA, 0, 0, 0);
        accB = __builtin_amdgcn_mfma_f32_16x16x32_f16(Bl1, ch1, accB, 0, 0, 0);
        accA = __builtin_amdgcn_mfma_f32_16x16x32_f16(Ah0, cl0, accA, 0, 0, 0);
        accB = __builtin_amdgcn_mfma_f32_16x16x32_f16(Bh0, cl0, accB, 0, 0, 0);
        accA = __builtin_amdgcn_mfma_f32_16x16x32_f16(Ah1, cl1, accA, 0, 0, 0);
        accB = __builtin_amdgcn_mfma_f32_16x16x32_f16(Bh1, cl1, accB, 0, 0, 0);
        accA = __builtin_amdgcn_mfma_f32_16x16x32_f16(Al0, cl0, accA, 0, 0, 0);
        accB = __builtin_amdgcn_mfma_f32_16x16x32_f16(Bl0, cl0, accB, 0, 0, 0);
        accA = __builtin_amdgcn_mfma_f32_16x16x32_f16(Al1, cl1, accA, 0, 0, 0);
        accB = __builtin_amdgcn_mfma_f32_16x16x32_f16(Bl1, cl1, accB, 0, 0, 0);

        const int vcode = ct + lane15;
#pragma unroll
        for (int r = 0; r < 4; ++r) {
            if (accA[r] > bvA[r]) { bvA[r] = accA[r]; biA[r] = vcode; }
            if (accB[r] > bvB[r]) { bvB[r] = accB[r]; biB[r] = vcode; }
        }

        // ---- rotate pipeline stages ----
        ch0 = nh0; ch1 = nh1; cl0 = nl0; cl1 = nl1; cn = cnn;
        nh0 = mh0; nh1 = mh1; nl0 = ml0; nl1 = ml1; cnn = cnm;
    }

    // ---- 16-lane butterfly per quad, then cross-wave LDS reduce ----
    __shared__ float rv[RPB][CWAVES + 1];
    __shared__ int   ri[RPB][CWAVES + 1];
    __shared__ int   sidx[RPB];
#pragma unroll
    for (int r = 0; r < 4; ++r) {
        float vA = bvA[r], vB = bvB[r];
        int  iA = biA[r], iB = biB[r];
#pragma unroll
        for (int m = 1; m < 16; m <<= 1) {
            float oA = __shfl_xor(vA, m, 64); int xA = __shfl_xor(iA, m, 64);
            if (oA > vA || (oA == vA && xA < iA)) { vA = oA; iA = xA; }
            float oB = __shfl_xor(vB, m, 64); int xB = __shfl_xor(iB, m, 64);
            if (oB > vB || (oB == vB && xB < iB)) { vB = oB; iB = xB; }
        }
        if (lane15 == 0) {
            rv[quad * 4 + r][w] = vA;      ri[quad * 4 + r][w] = iA;
            rv[16 + quad * 4 + r][w] = vB; ri[16 + quad * 4 + r][w] = iB;
        }
    }
    __syncthreads();   // drains NT zero stores before the 1.0 write
    if (t < RPB) {
        float bv = rv[t][0];
        int   bi = ri[t][0];
#pragma unroll
        for (int w2 = 1; w2 < CWAVES; ++w2) {  // ascending wave = ascending codes
            float v = rv[t][w2];
            int  id = ri[t][w2];
            if (v > bv || (v == bv && id < bi)) { bv = v; bi = id; }
        }
        int row = row0 + t;
        sidx[t] = bi;
        discrete[(size_t)row * KCODES + bi] = 1.0f;
    }
    __syncthreads();

    // ---- fused quantized gather: 32 rows x 16 float4, coalesced ----
    if (t < RPB * 16) {
        int r = t >> 4, c = t & 15;
        float4 v = *((const float4*)(cb + (size_t)sidx[r] * DDIM) + c);
        *((float4*)(quantized + (size_t)(row0 + r) * DDIM) + c) = v;
    }
}

extern "C" void kernel_launch(void* const* d_in, const int* in_sizes, int n_in,
                              void* d_out, int out_size, void* d_ws, size_t ws_size,
                              hipStream_t stream) {
    const float* x  = (const float*)d_in[0];   // 16*32*32*64
    const float* cb = (const float*)d_in[1];   // 8192*64

    float* discrete  = (float*)d_out;                          // 16384*8192
    float* quantized = (float*)d_out + (size_t)NROWS * KCODES; // 16384*64

    // workspace layout: cn2 (32 KB) | packed B-frags (2 MB).
    float* cn2    = (float*)d_ws;              // 8192 floats
    f16x8* packed = (f16x8*)(cn2 + KCODES);    // 2 MB

    k_prep<<<(KCODES / 16) * 64 / 256, 256, 0, stream>>>(cb, packed, cn2);
    k_main<<<NROWS / RPB, CWAVES * 64, 0, stream>>>(x, cb, packed, cn2,
                                                    discrete, quantized);
}